// Round 1
// baseline (464.389 us; speedup 1.0000x reference)
//
#include <hip/hip_runtime.h>
#include <hip/hip_bf16.h>

#define PED   512
#define HDIM  64
#define EDIM  32
#define NPAIR (PED * PED)          // 262144 rows
#define GATES 256                  // 4*H
#define KDIM  96                   // E + H
#define BS    104                  // Blds row stride (bf16): 208 B -> 16B-aligned, ~2-way banks
#define TILES_PER_BLOCK 4
#define NBLOCKS (NPAIR / (TILES_PER_BLOCK * 64))   // 1024

typedef __attribute__((ext_vector_type(8))) __bf16 bf16x8;
typedef __attribute__((ext_vector_type(4))) float  floatx4;

__device__ __forceinline__ float sigmoidf_fast(float x) {
    return 1.0f / (1.0f + __expf(-x));
}
__device__ __forceinline__ float tanhf_fast(float x) {
    // 2/(1+e^-2x) - 1 ; saturates correctly at +-1 via inf
    return 2.0f / (1.0f + __expf(-2.0f * x)) - 1.0f;
}

__global__ __launch_bounds__(256, 2)
void sra_lstm_kernel(const float* __restrict__ corr,   // [P*P, 2]
                     const float* __restrict__ ht,     // [P*P, 64]
                     const float* __restrict__ ct,     // [P*P, 64]
                     const int*   __restrict__ nei,    // [P*P]
                     const float* __restrict__ W_emb,  // [32, 2]
                     const float* __restrict__ b_emb,  // [32]
                     const float* __restrict__ W_ih,   // [256, 32]
                     const float* __restrict__ W_hh,   // [256, 64]
                     const float* __restrict__ b_ih,   // [256]
                     const float* __restrict__ b_hh,   // [256]
                     float* __restrict__ h_out,        // [P*P, 64]
                     float* __restrict__ c_out)        // [P*P, 64]
{
    // B operand: B[k][n] = W_cat[n][k], stored [n][k] bf16, padded stride.
    __shared__ __align__(16) __bf16 Blds[GATES * BS];  // 53248 B
    __shared__ float bsum[GATES];                      // b_ih + b_hh

    const int tid  = threadIdx.x;
    const int wave = tid >> 6;
    const int lane = tid & 63;
    const int lo   = lane & 15;   // MFMA "row/col within 16" index
    const int qu   = lane >> 4;   // MFMA quad index

    // ---- once per block: weights -> LDS (fp32 -> bf16), bias sums ----
    for (int idx = tid; idx < GATES * KDIM; idx += 256) {
        int n = idx / KDIM;
        int k = idx - n * KDIM;
        float w = (k < EDIM) ? W_ih[n * EDIM + k] : W_hh[n * HDIM + (k - EDIM)];
        Blds[n * BS + k] = (__bf16)w;
    }
    bsum[tid] = b_ih[tid] + b_hh[tid];

    // per-lane W_emb slice: A-frag0 element j covers e = qu*8 + j
    float wex[8], wey[8], beb[8];
#pragma unroll
    for (int j = 0; j < 8; ++j) {
        int e = qu * 8 + j;
        wex[j] = W_emb[e * 2 + 0];
        wey[j] = W_emb[e * 2 + 1];
        beb[j] = b_emb[e];
    }
    __syncthreads();

    for (int t = 0; t < TILES_PER_BLOCK; ++t) {
        const int rb    = (blockIdx.x * TILES_PER_BLOCK + t) * 64 + wave * 16;
        const int row_a = rb + lo;     // A-operand row this lane loads

        // ---- A frag 0: embedding, k in [0,32) ----
        float2 x = *(const float2*)(corr + (size_t)row_a * 2);
        bf16x8 a0;
#pragma unroll
        for (int j = 0; j < 8; ++j) {
            float v = fmaf(x.x, wex[j], fmaf(x.y, wey[j], beb[j]));
            a0[j] = (__bf16)fmaxf(v, 0.0f);
        }

        // ---- A frags 1,2: h, k in [32,96) ----
        const float* hp = ht + (size_t)row_a * HDIM + qu * 8;
        float4 h0a = *(const float4*)(hp);
        float4 h0b = *(const float4*)(hp + 4);
        float4 h1a = *(const float4*)(hp + 32);
        float4 h1b = *(const float4*)(hp + 36);
        bf16x8 a1, a2;
        a1[0] = (__bf16)h0a.x; a1[1] = (__bf16)h0a.y;
        a1[2] = (__bf16)h0a.z; a1[3] = (__bf16)h0a.w;
        a1[4] = (__bf16)h0b.x; a1[5] = (__bf16)h0b.y;
        a1[6] = (__bf16)h0b.z; a1[7] = (__bf16)h0b.w;
        a2[0] = (__bf16)h1a.x; a2[1] = (__bf16)h1a.y;
        a2[2] = (__bf16)h1a.z; a2[3] = (__bf16)h1a.w;
        a2[4] = (__bf16)h1b.x; a2[5] = (__bf16)h1b.y;
        a2[6] = (__bf16)h1b.z; a2[7] = (__bf16)h1b.w;

        // ---- GEMM: 16 rows x 256 gates, K=96 ----
        floatx4 acc[16];
#pragma unroll
        for (int nt = 0; nt < 16; ++nt) {
            const __bf16* bp = Blds + (nt * 16 + lo) * BS + qu * 8;
            bf16x8 b0 = *(const bf16x8*)(bp);
            bf16x8 b1 = *(const bf16x8*)(bp + 32);
            bf16x8 b2 = *(const bf16x8*)(bp + 64);
            floatx4 c = {0.f, 0.f, 0.f, 0.f};
            c = __builtin_amdgcn_mfma_f32_16x16x32_bf16(a0, b0, c, 0, 0, 0);
            c = __builtin_amdgcn_mfma_f32_16x16x32_bf16(a1, b1, c, 0, 0, 0);
            c = __builtin_amdgcn_mfma_f32_16x16x32_bf16(a2, b2, c, 0, 0, 0);
            acc[nt] = c;
        }

        // ---- epilogue: gates -> LSTM update -> masked writeback ----
        // C/D layout: n = nt*16 + lo, row m = qu*4 + reg.
        // gate sections: i = n in [0,64), f = [64,128), g = [128,192), o = [192,256)
#pragma unroll
        for (int tt = 0; tt < 4; ++tt) {
            const int k   = tt * 16 + lo;   // hidden index
            const float bi  = bsum[k];
            const float bff = bsum[64 + k];
            const float bg  = bsum[128 + k];
            const float bo  = bsum[192 + k];
#pragma unroll
            for (int r = 0; r < 4; ++r) {
                const int row = rb + qu * 4 + r;
                const size_t off = (size_t)row * HDIM + k;
                float iv = sigmoidf_fast(acc[tt][r] + bi);
                float fv = sigmoidf_fast(acc[4 + tt][r] + bff);
                float gv = tanhf_fast(acc[8 + tt][r] + bg);
                float ov = sigmoidf_fast(acc[12 + tt][r] + bo);
                float cold = ct[off];
                float cn = fv * cold + iv * gv;
                float hn = ov * tanhf_fast(cn);
                bool msk = nei[row] > 0;
                float hold = ht[off];      // L2-hot: same tile read for A-frags
                h_out[off] = msk ? hn : hold;
                c_out[off] = msk ? cn : cold;
            }
        }
    }
}

extern "C" void kernel_launch(void* const* d_in, const int* in_sizes, int n_in,
                              void* d_out, int out_size, void* d_ws, size_t ws_size,
                              hipStream_t stream) {
    const float* corr  = (const float*)d_in[0];
    const float* ht    = (const float*)d_in[1];
    const float* ct    = (const float*)d_in[2];
    const int*   nei   = (const int*)  d_in[3];
    const float* W_emb = (const float*)d_in[4];
    const float* b_emb = (const float*)d_in[5];
    const float* W_ih  = (const float*)d_in[6];
    const float* W_hh  = (const float*)d_in[7];
    const float* b_ih  = (const float*)d_in[8];
    const float* b_hh  = (const float*)d_in[9];

    float* hout = (float*)d_out;
    float* cout = hout + (size_t)NPAIR * HDIM;

    hipLaunchKernelGGL(sra_lstm_kernel, dim3(NBLOCKS), dim3(256), 0, stream,
                       corr, ht, ct, nei, W_emb, b_emb, W_ih, W_hh, b_ih, b_hh,
                       hout, cout);
}

// Round 2
// 310.515 us; speedup vs baseline: 1.4955x; 1.4955x over previous
//
#include <hip/hip_runtime.h>
#include <hip/hip_bf16.h>

#define PED   512
#define HDIM  64
#define EDIM  32
#define NPAIR (PED * PED)          // 262144 rows
#define GATES 256                  // 4*H
#define WF_ELEMS (16 * 64 * 24)    // B frags: [nt][lane][kstep*8+jj], bf16
#define OS    68                   // LDS out-tile row stride in floats (272 B, 16B-aligned)

typedef __attribute__((ext_vector_type(8))) __bf16 bf16x8;
typedef __attribute__((ext_vector_type(4))) float  floatx4;

__device__ __forceinline__ float sigmoidf_fast(float x) {
    return 1.0f / (1.0f + __expf(-x));
}
__device__ __forceinline__ float tanhf_fast(float x) {
    return 2.0f / (1.0f + __expf(-2.0f * x)) - 1.0f;
}

// ---- prep: weights -> bf16 MFMA B-fragment order in d_ws, bias sums ----
// Wf[(nt*64 + lane)*24 + kstep*8 + jj] = W_cat[nt*16 + (lane&15)][kstep*32 + (lane>>4)*8 + jj]
__global__ void sra_prep(const float* __restrict__ W_ih, const float* __restrict__ W_hh,
                         const float* __restrict__ b_ih, const float* __restrict__ b_hh,
                         __bf16* __restrict__ Wf, float* __restrict__ bsum)
{
    int tid = blockIdx.x * 256 + threadIdx.x;
    if (tid < WF_ELEMS) {
        int m    = tid % 24;
        int nl   = tid / 24;
        int lane = nl & 63;
        int nt   = nl >> 6;
        int n = nt * 16 + (lane & 15);
        int k = (m >> 3) * 32 + (lane >> 4) * 8 + (m & 7);
        float w = (k < EDIM) ? W_ih[n * EDIM + k] : W_hh[n * HDIM + (k - EDIM)];
        Wf[tid] = (__bf16)w;
    }
    if (tid < GATES) bsum[tid] = b_ih[tid] + b_hh[tid];
}

// ---- main: one 16-row tile per wave, 4 waves/block, 4096 blocks ----
__global__ __launch_bounds__(256, 4)
void sra_main(const float* __restrict__ corr,   // [P*P, 2]
              const float* __restrict__ ht,     // [P*P, 64]
              const float* __restrict__ ct,     // [P*P, 64]
              const int*   __restrict__ nei,    // [P*P]
              const float* __restrict__ W_emb,  // [32, 2]
              const float* __restrict__ b_emb,  // [32]
              const __bf16* __restrict__ Wf,    // [16*64*24] frag-order weights
              const float* __restrict__ bsumg,  // [256]
              float* __restrict__ h_out,
              float* __restrict__ c_out)
{
    __shared__ float bsum[GATES];
    __shared__ __align__(16) float OhS[4][16 * OS];   // per-wave h tile (in: h_old, out: h result)
    __shared__ __align__(16) float OcS[4][16 * OS];   // per-wave c tile

    const int tid  = threadIdx.x;
    const int wave = tid >> 6;
    const int lane = tid & 63;
    const int lo   = lane & 15;
    const int qu   = lane >> 4;

    bsum[tid] = bsumg[tid];
    __syncthreads();   // only block-level barrier

    float* oh = &OhS[wave][0];
    float* oc = &OcS[wave][0];

    const int tile = blockIdx.x * 4 + wave;   // 0..16383
    const int rb   = tile * 16;

    // ---- A frag 0: embedding, k in [0,32) ----
    float2 x = *(const float2*)(corr + (size_t)(rb + lo) * 2);
    bf16x8 a0;
#pragma unroll
    for (int j = 0; j < 8; ++j) {
        int e = qu * 8 + j;
        float v = fmaf(x.x, W_emb[e * 2 + 0], fmaf(x.y, W_emb[e * 2 + 1], b_emb[e]));
        a0[j] = (__bf16)fmaxf(v, 0.0f);
    }

    // ---- load h/c tile (16B/lane, full lines), stage fp32 into wave-local LDS ----
    const size_t rowoff = (size_t)(rb + lo) * HDIM + qu * 8;
    float4 h0a = *(const float4*)(ht + rowoff);
    float4 h0b = *(const float4*)(ht + rowoff + 4);
    float4 h1a = *(const float4*)(ht + rowoff + 32);
    float4 h1b = *(const float4*)(ht + rowoff + 36);
    float4 c0a = *(const float4*)(ct + rowoff);
    float4 c0b = *(const float4*)(ct + rowoff + 4);
    float4 c1a = *(const float4*)(ct + rowoff + 32);
    float4 c1b = *(const float4*)(ct + rowoff + 36);

    float* ohr = oh + lo * OS + qu * 8;
    float* ocr = oc + lo * OS + qu * 8;
    *(float4*)(ohr)      = h0a;  *(float4*)(ohr + 4)  = h0b;
    *(float4*)(ohr + 32) = h1a;  *(float4*)(ohr + 36) = h1b;
    *(float4*)(ocr)      = c0a;  *(float4*)(ocr + 4)  = c0b;
    *(float4*)(ocr + 32) = c1a;  *(float4*)(ocr + 36) = c1b;

    // ---- A frags 1,2: h bf16, k in [32,96) ----
    bf16x8 a1, a2;
    a1[0] = (__bf16)h0a.x; a1[1] = (__bf16)h0a.y; a1[2] = (__bf16)h0a.z; a1[3] = (__bf16)h0a.w;
    a1[4] = (__bf16)h0b.x; a1[5] = (__bf16)h0b.y; a1[6] = (__bf16)h0b.z; a1[7] = (__bf16)h0b.w;
    a2[0] = (__bf16)h1a.x; a2[1] = (__bf16)h1a.y; a2[2] = (__bf16)h1a.z; a2[3] = (__bf16)h1a.w;
    a2[4] = (__bf16)h1b.x; a2[5] = (__bf16)h1b.y; a2[6] = (__bf16)h1b.z; a2[7] = (__bf16)h1b.w;

    // ---- GEMM: 16 rows x 256 gates, K=96; B frags streamed from global (L1/L2-hot) ----
    floatx4 acc[16];
    const __bf16* bbase = Wf + lane * 24;
#pragma unroll
    for (int nt = 0; nt < 16; ++nt) {
        const __bf16* bp = bbase + nt * 1536;
        bf16x8 b0 = *(const bf16x8*)(bp);
        bf16x8 b1 = *(const bf16x8*)(bp + 8);
        bf16x8 b2 = *(const bf16x8*)(bp + 16);
        floatx4 c = {0.f, 0.f, 0.f, 0.f};
        c = __builtin_amdgcn_mfma_f32_16x16x32_bf16(a0, b0, c, 0, 0, 0);
        c = __builtin_amdgcn_mfma_f32_16x16x32_bf16(a1, b1, c, 0, 0, 0);
        c = __builtin_amdgcn_mfma_f32_16x16x32_bf16(a2, b2, c, 0, 0, 0);
        acc[nt] = c;
    }

    // ---- epilogue in C-layout: n = nt*16 + lo, local row = qu*4 + r ----
    int msk[4];
#pragma unroll
    for (int r = 0; r < 4; ++r) msk[r] = nei[rb + qu * 4 + r];

#pragma unroll
    for (int tt = 0; tt < 4; ++tt) {
        const int k = tt * 16 + lo;
        const float bi  = bsum[k];
        const float bff = bsum[64 + k];
        const float bg  = bsum[128 + k];
        const float bo  = bsum[192 + k];
#pragma unroll
        for (int r = 0; r < 4; ++r) {
            const int rl = qu * 4 + r;
            float hold = oh[rl * OS + k];
            float cold = oc[rl * OS + k];
            float iv = sigmoidf_fast(acc[tt][r] + bi);
            float fv = sigmoidf_fast(acc[4 + tt][r] + bff);
            float gv = tanhf_fast(acc[8 + tt][r] + bg);
            float ov = sigmoidf_fast(acc[12 + tt][r] + bo);
            float cn = fv * cold + iv * gv;
            float hn = ov * tanhf_fast(cn);
            bool m = msk[r] > 0;
            oh[rl * OS + k] = m ? hn : hold;
            oc[rl * OS + k] = m ? cn : cold;
        }
    }

    // ---- coalesced full-line stores: 1 KB contiguous per instruction ----
    float* hbase = h_out + (size_t)rb * HDIM;
    float* cbase = c_out + (size_t)rb * HDIM;
#pragma unroll
    for (int j = 0; j < 4; ++j) {
        int fi  = j * 64 + lane;          // float4 index within tile (0..255)
        int row = fi >> 4;
        int c4  = fi & 15;
        float4 vh = *(float4*)(oh + row * OS + c4 * 4);
        float4 vc = *(float4*)(oc + row * OS + c4 * 4);
        *(float4*)(hbase + fi * 4) = vh;
        *(float4*)(cbase + fi * 4) = vc;
    }
}

extern "C" void kernel_launch(void* const* d_in, const int* in_sizes, int n_in,
                              void* d_out, int out_size, void* d_ws, size_t ws_size,
                              hipStream_t stream) {
    const float* corr  = (const float*)d_in[0];
    const float* ht    = (const float*)d_in[1];
    const float* ct    = (const float*)d_in[2];
    const int*   nei   = (const int*)  d_in[3];
    const float* W_emb = (const float*)d_in[4];
    const float* b_emb = (const float*)d_in[5];
    const float* W_ih  = (const float*)d_in[6];
    const float* W_hh  = (const float*)d_in[7];
    const float* b_ih  = (const float*)d_in[8];
    const float* b_hh  = (const float*)d_in[9];

    __bf16* Wf   = (__bf16*)d_ws;                        // 49152 B
    float*  bsum = (float*)((char*)d_ws + WF_ELEMS * 2); // 1024 B

    float* hout = (float*)d_out;
    float* cout = hout + (size_t)NPAIR * HDIM;

    hipLaunchKernelGGL(sra_prep, dim3(96), dim3(256), 0, stream,
                       W_ih, W_hh, b_ih, b_hh, Wf, bsum);
    hipLaunchKernelGGL(sra_main, dim3(NPAIR / 64), dim3(256), 0, stream,
                       corr, ht, ct, nei, W_emb, b_emb, Wf, bsum, hout, cout);
}